// Round 1
// baseline (2043.525 us; speedup 1.0000x reference)
//
#include <hip/hip_runtime.h>

#define S_STEPS 8
#define D 128

typedef __attribute__((ext_vector_type(4))) float f32x4;
typedef __attribute__((ext_vector_type(4))) short s16x4;
typedef __attribute__((ext_vector_type(8))) short s16x8;

static __device__ __forceinline__ short f2bf(float f) {
    union { float f; unsigned u; } x; x.f = f;
    unsigned r = x.u + 0x7fffu + ((x.u >> 16) & 1u);
    return (short)(r >> 16);
}

__global__ void count_kernel(const int* __restrict__ dst, int* __restrict__ cnt, int E) {
    int e = blockIdx.x * blockDim.x + threadIdx.x;
    if (e < E) atomicAdd(&cnt[dst[e]], 1);
}

// Single-block inclusive scan over cnt -> row_ptr (exclusive), fill init, rdeg
__global__ void scan_kernel(const int* __restrict__ cnt, int* __restrict__ row_ptr,
                            int* __restrict__ fill, float* __restrict__ rdeg,
                            int N, int E) {
    __shared__ int buf[1024];
    __shared__ int carry_s;
    const int tid = threadIdx.x;
    if (tid == 0) carry_s = 0;
    __syncthreads();
    for (int base = 0; base < N; base += 1024) {
        int i = base + tid;
        int v = (i < N) ? cnt[i] : 0;
        buf[tid] = v;
        __syncthreads();
        for (int off = 1; off < 1024; off <<= 1) {
            int t = (tid >= off) ? buf[tid - off] : 0;
            __syncthreads();
            buf[tid] += t;
            __syncthreads();
        }
        int incl = buf[tid];
        int carry = carry_s;
        int excl = carry + incl - v;
        if (i < N) {
            row_ptr[i] = excl;
            fill[i] = excl;
            rdeg[i] = 1.0f / (float)((v > 1) ? v : 1);
        }
        __syncthreads();               // everyone read carry_s before update
        if (tid == 1023) carry_s = carry + incl;
        __syncthreads();
    }
    if (tid == 0) row_ptr[N] = E;
}

__global__ void fill_kernel(const int* __restrict__ src, const int* __restrict__ dst,
                            int* __restrict__ fill, int* __restrict__ eidx, int E) {
    int e = blockIdx.x * blockDim.x + threadIdx.x;
    if (e < E) {
        int p = atomicAdd(&fill[dst[e]], 1);
        eidx[p] = src[e];
    }
}

// C[N,256] = bf16(x[N,128]) @ bf16([Wl^T | Wr^T])
// cols 0..127 -> h (stored bf16 in ws), cols 128..255 -> base = x@Wr^T + b_l (to d_out)
__global__ __launch_bounds__(256) void lin_kernel(const float* __restrict__ x,
    const float* __restrict__ Wl, const float* __restrict__ Wr,
    const float* __restrict__ bl,
    unsigned short* __restrict__ hbf, float* __restrict__ outb, int N)
{
    // pitch 136 bf16 elems: word-pitch 68 -> bank spread, 16B alignment everywhere
    __shared__ __align__(16) short As[64 * 136];
    __shared__ __align__(16) short Bs[256 * 136];
    __shared__ float bls[128];

    const int tid = threadIdx.x;
    const int row0 = blockIdx.x * 64;

    // stage W (B^T rows = W rows, so store row-major as-is): 256x128 fp32 -> bf16
#pragma unroll
    for (int it = 0; it < 32; ++it) {
        int i = tid + it * 256;            // 0..8191
        int j = i >> 5;                    // B row (output col) 0..255
        int kq = i & 31;                   // float4 index along K
        const float* srcp = (j < 128) ? (Wl + j * 128 + kq * 4)
                                      : (Wr + (size_t)(j - 128) * 128 + kq * 4);
        float4 v = *(const float4*)srcp;
        s16x4 b; b.x = f2bf(v.x); b.y = f2bf(v.y); b.z = f2bf(v.z); b.w = f2bf(v.w);
        *(s16x4*)&Bs[j * 136 + kq * 4] = b;
    }
    if (tid < 128) bls[tid] = bl[tid];

    // stage A: 64 rows of x
#pragma unroll
    for (int it = 0; it < 8; ++it) {
        int i = tid + it * 256;            // 0..2047
        int r = i >> 5;                    // local row
        int kq = i & 31;
        int grow = row0 + r;
        float4 v = make_float4(0.f, 0.f, 0.f, 0.f);
        if (grow < N) v = *(const float4*)(x + (size_t)grow * 128 + kq * 4);
        s16x4 a; a.x = f2bf(v.x); a.y = f2bf(v.y); a.z = f2bf(v.z); a.w = f2bf(v.w);
        *(s16x4*)&As[r * 136 + kq * 4] = a;
    }
    __syncthreads();

    const int lane = tid & 63;
    const int wave = tid >> 6;
    const int m = lane & 15;           // A row within tile / B col within tile
    const int q = lane >> 4;           // quad -> k offset q*8, D row base q*4

    f32x4 acc[16];
#pragma unroll
    for (int i = 0; i < 16; ++i) acc[i] = (f32x4){0.f, 0.f, 0.f, 0.f};

    const short* aptr = &As[(wave * 16 + m) * 136 + q * 8];
    const short* bptr = &Bs[m * 136 + q * 8];
#pragma unroll
    for (int kc = 0; kc < 128; kc += 32) {
        s16x8 afrag = *(const s16x8*)(aptr + kc);
#pragma unroll
        for (int ct = 0; ct < 16; ++ct) {
            s16x8 bfrag = *(const s16x8*)(bptr + ct * 16 * 136 + kc);
            acc[ct] = __builtin_amdgcn_mfma_f32_16x16x32_bf16(afrag, bfrag, acc[ct], 0, 0, 0);
        }
    }

    const int rowbase = row0 + wave * 16 + q * 4;
#pragma unroll
    for (int ct = 0; ct < 16; ++ct) {
        int col = ct * 16 + m;
#pragma unroll
        for (int r = 0; r < 4; ++r) {
            int rr = rowbase + r;
            if (rr < N) {
                if (col < 128) {
                    hbf[(size_t)rr * 128 + col] = (unsigned short)f2bf(acc[ct][r]);
                } else {
                    outb[(size_t)rr * 128 + (col - 128)] = acc[ct][r] + bls[col - 128];
                }
            }
        }
    }
}

// per-node CSR gather of h (bf16), add base (in d_out), fused ys projection
__global__ __launch_bounds__(256) void agg_kernel(const unsigned short* __restrict__ hbf,
    const int* __restrict__ row_ptr, const int* __restrict__ eidx,
    const float* __restrict__ rdeg, const float* __restrict__ wfc,
    const float* __restrict__ bfc, float* __restrict__ outb,
    float* __restrict__ ys, int N)
{
    const int lane = threadIdx.x & 63;
    const int wave = threadIdx.x >> 6;
    const int node = blockIdx.x * 4 + wave;
    if (node >= N) return;
    const int beg = row_ptr[node];
    const int end = row_ptr[node + 1];
    float ax = 0.f, ay = 0.f;
    for (int e = beg; e < end; ++e) {
        int s = eidx[e];
        unsigned pk = *(const unsigned*)(hbf + (size_t)s * 128 + lane * 2);
        union { unsigned u; float f; } lo, hi;
        lo.u = pk << 16;
        hi.u = pk & 0xffff0000u;
        ax += lo.f; ay += hi.f;
    }
    const float rd = rdeg[node];
    const float2 base = *(const float2*)(outb + (size_t)node * 128 + lane * 2);
    float ox = base.x + ax * rd;
    float oy = base.y + ay * rd;
    *(float2*)(outb + (size_t)node * 128 + lane * 2) = make_float2(ox, oy);

    const float2 w = *(const float2*)(wfc + lane * 2);
    float p = ox * w.x + oy * w.y;
#pragma unroll
    for (int off = 32; off > 0; off >>= 1) p += __shfl_down(p, off);
    if (lane == 0) ys[node] = p + bfc[0];
}

extern "C" void kernel_launch(void* const* d_in, const int* in_sizes, int n_in,
                              void* d_out, int out_size, void* d_ws, size_t ws_size,
                              hipStream_t stream)
{
    const float* x   = (const float*)d_in[0];
    const int*   ei  = (const int*)d_in[1];
    const float* Wl  = (const float*)d_in[2];
    const float* bl  = (const float*)d_in[3];
    const float* Wr  = (const float*)d_in[4];
    const float* Wfc = (const float*)d_in[5];
    const float* bfc = (const float*)d_in[6];

    const int N = in_sizes[0] / (S_STEPS * D);
    const int E = in_sizes[1] / 2;
    const int* srcp = ei;
    const int* dstp = ei + E;

    char* p = (char*)d_ws;
    auto alloc = [&](size_t bytes) {
        char* r = p;
        p += (bytes + 255) & ~(size_t)255;
        return r;
    };
    int*   cnt     = (int*)alloc((size_t)N * 4);
    int*   row_ptr = (int*)alloc((size_t)(N + 1) * 4);
    int*   fill    = (int*)alloc((size_t)N * 4);
    float* rdeg    = (float*)alloc((size_t)N * 4);
    int*   eidx    = (int*)alloc((size_t)E * 4);
    unsigned short* hbf = (unsigned short*)alloc((size_t)N * D * 2);
    (void)ws_size;

    float* xs    = (float*)d_out;
    float* ysall = xs + (size_t)S_STEPS * N * D;

    hipMemsetAsync(cnt, 0, (size_t)N * 4, stream);
    count_kernel<<<(E + 255) / 256, 256, 0, stream>>>(dstp, cnt, E);
    scan_kernel<<<1, 1024, 0, stream>>>(cnt, row_ptr, fill, rdeg, N, E);
    fill_kernel<<<(E + 255) / 256, 256, 0, stream>>>(srcp, dstp, fill, eidx, E);

    const int gl = (N + 63) / 64;
    const int ga = (N + 3) / 4;
    for (int t = 0; t < S_STEPS; ++t) {
        const float* xt = x + (size_t)t * N * D;
        float* outb = xs + (size_t)t * N * D;
        lin_kernel<<<gl, 256, 0, stream>>>(xt, Wl, Wr, bl, hbf, outb, N);
        agg_kernel<<<ga, 256, 0, stream>>>(hbf, row_ptr, eidx, rdeg, Wfc, bfc,
                                           outb, ysall + (size_t)t * N, N);
    }
}

// Round 2
// 1167.465 us; speedup vs baseline: 1.7504x; 1.7504x over previous
//
#include <hip/hip_runtime.h>

#define S_STEPS 8
#define D 128

typedef __attribute__((ext_vector_type(4))) float f32x4;
typedef __attribute__((ext_vector_type(4))) short s16x4;
typedef __attribute__((ext_vector_type(8))) short s16x8;

static __device__ __forceinline__ short f2bf(float f) {
    union { float f; unsigned u; } x; x.f = f;
    unsigned r = x.u + 0x7fffu + ((x.u >> 16) & 1u);
    return (short)(r >> 16);
}

__global__ void count_kernel(const int* __restrict__ dst, int* __restrict__ cnt, int E) {
    int e = blockIdx.x * blockDim.x + threadIdx.x;
    if (e < E) atomicAdd(&cnt[dst[e]], 1);
}

// bf16 conversion of [Wl;Wr] -> wbf[256][128], once per call
__global__ void cvtw_kernel(const float* __restrict__ Wl, const float* __restrict__ Wr,
                            unsigned short* __restrict__ wbf) {
    int i = blockIdx.x * blockDim.x + threadIdx.x;   // 0..32767
    if (i < 256 * 128) {
        int j = i >> 7, k = i & 127;
        float v = (j < 128) ? Wl[j * 128 + k] : Wr[(j - 128) * 128 + k];
        wbf[i] = (unsigned short)f2bf(v);
    }
}

// Single-block scan over cnt -> row_ptr (exclusive), fill init, rdeg. Shuffle-based.
__global__ __launch_bounds__(1024) void scan_kernel(const int* __restrict__ cnt,
                            int* __restrict__ row_ptr,
                            int* __restrict__ fill, float* __restrict__ rdeg,
                            int N, int E) {
    __shared__ int wsum[16];
    __shared__ int woff[16];
    __shared__ int carry_s;
    const int tid = threadIdx.x;
    const int lane = tid & 63;
    const int wv = tid >> 6;
    if (tid == 0) carry_s = 0;
    __syncthreads();
    for (int base = 0; base < N; base += 1024) {
        int i = base + tid;
        int v = (i < N) ? cnt[i] : 0;
        int inc = v;
#pragma unroll
        for (int off = 1; off < 64; off <<= 1) {
            int t = __shfl_up(inc, off);
            if (lane >= off) inc += t;
        }
        if (lane == 63) wsum[wv] = inc;
        __syncthreads();
        if (wv == 0 && lane < 16) {
            int s = wsum[lane];
            int in2 = s;
#pragma unroll
            for (int off = 1; off < 16; off <<= 1) {
                int t = __shfl_up(in2, off);
                if (lane >= off) in2 += t;
            }
            woff[lane] = in2 - s;   // exclusive wave offset
        }
        __syncthreads();
        int carry = carry_s;
        int excl = carry + woff[wv] + inc - v;
        if (i < N) {
            row_ptr[i] = excl;
            fill[i] = excl;
            rdeg[i] = 1.0f / (float)((v > 1) ? v : 1);
        }
        __syncthreads();            // everyone read carry_s before update
        if (tid == 1023) carry_s = carry + woff[15] + inc;
        __syncthreads();
    }
    if (tid == 0) row_ptr[N] = E;
}

__global__ void fill_kernel(const int* __restrict__ src, const int* __restrict__ dst,
                            int* __restrict__ fill, int* __restrict__ eidx, int E) {
    int e = blockIdx.x * blockDim.x + threadIdx.x;
    if (e < E) {
        int p = atomicAdd(&fill[dst[e]], 1);
        eidx[p] = src[e];
    }
}

// C[N,256] = bf16(x[N,128]) @ wbf^T. Waves 0,1 -> cols 0..127 -> hbf;
// waves 2,3 -> cols 128..255 -> outb = x@Wr^T + b_l.
// B fragments live in registers (64 VGPR/wave); only A tile staged in LDS.
__global__ __launch_bounds__(256) void lin_kernel(const float* __restrict__ x,
    const unsigned short* __restrict__ wbf, const float* __restrict__ bl,
    unsigned short* __restrict__ hbf, float* __restrict__ outb, int N)
{
    __shared__ __align__(16) short As[64 * 136];   // pitch 136 -> bank spread
    __shared__ float bls[128];

    const int tid = threadIdx.x;
    const int row0 = blockIdx.x * 64;
    const int lane = tid & 63;
    const int w = tid >> 6;
    const int m = lane & 15;
    const int q = lane >> 4;

    // B register staging: wave w owns cols w*64 .. w*64+63 (4 col-tiles)
    s16x8 bf[4][4];
#pragma unroll
    for (int ct = 0; ct < 4; ++ct) {
#pragma unroll
        for (int kc = 0; kc < 4; ++kc) {
            int col = (w * 4 + ct) * 16 + m;
            bf[ct][kc] = *(const s16x8*)(wbf + (size_t)col * 128 + kc * 32 + q * 8);
        }
    }
    if (tid < 128) bls[tid] = bl[tid];

    // stage A: 64 rows of x, fp32 -> bf16 LDS
#pragma unroll
    for (int it = 0; it < 8; ++it) {
        int i = tid + it * 256;            // 0..2047
        int r = i >> 5;                    // local row
        int kq = i & 31;                   // float4 index along K
        int grow = row0 + r;
        float4 v = make_float4(0.f, 0.f, 0.f, 0.f);
        if (grow < N) v = *(const float4*)(x + (size_t)grow * 128 + kq * 4);
        s16x4 a; a.x = f2bf(v.x); a.y = f2bf(v.y); a.z = f2bf(v.z); a.w = f2bf(v.w);
        *(s16x4*)&As[r * 136 + kq * 4] = a;
    }
    __syncthreads();

    f32x4 acc[4][4];
#pragma unroll
    for (int i = 0; i < 4; ++i)
#pragma unroll
        for (int j = 0; j < 4; ++j) acc[i][j] = (f32x4){0.f, 0.f, 0.f, 0.f};

#pragma unroll
    for (int mt = 0; mt < 4; ++mt) {
        s16x8 af[4];
#pragma unroll
        for (int kc = 0; kc < 4; ++kc)
            af[kc] = *(const s16x8*)&As[(mt * 16 + m) * 136 + kc * 32 + q * 8];
#pragma unroll
        for (int ct = 0; ct < 4; ++ct)
#pragma unroll
            for (int kc = 0; kc < 4; ++kc)
                acc[mt][ct] = __builtin_amdgcn_mfma_f32_16x16x32_bf16(
                    af[kc], bf[ct][kc], acc[mt][ct], 0, 0, 0);
    }

    const int colbase = w * 64;
#pragma unroll
    for (int mt = 0; mt < 4; ++mt) {
        const int rowbase = row0 + mt * 16 + q * 4;
#pragma unroll
        for (int ct = 0; ct < 4; ++ct) {
            int col = colbase + ct * 16 + m;
#pragma unroll
            for (int r = 0; r < 4; ++r) {
                int rr = rowbase + r;
                if (rr < N) {
                    if (col < 128) {
                        hbf[(size_t)rr * 128 + col] = (unsigned short)f2bf(acc[mt][ct][r]);
                    } else {
                        outb[(size_t)rr * 128 + (col - 128)] = acc[mt][ct][r] + bls[col - 128];
                    }
                }
            }
        }
    }
}

// per-node CSR gather of h (bf16). 4 edges per wave-iteration, dwordx4/lane.
// lane = g*16 + l: group g handles edges beg+g, beg+g+4, ...; slice l -> features l*8..l*8+7
__global__ __launch_bounds__(256) void agg_kernel(const unsigned short* __restrict__ hbf,
    const int* __restrict__ row_ptr, const int* __restrict__ eidx,
    const float* __restrict__ rdeg, const float* __restrict__ wfc,
    const float* __restrict__ bfc, float* __restrict__ outb,
    float* __restrict__ ys, int N)
{
    const int lane = threadIdx.x & 63;
    const int wv = threadIdx.x >> 6;
    const int node = blockIdx.x * 4 + wv;
    if (node >= N) return;
    const int g = lane >> 4;
    const int l = lane & 15;
    const int beg = row_ptr[node];
    const int end = row_ptr[node + 1];

    float acc[8];
#pragma unroll
    for (int j = 0; j < 8; ++j) acc[j] = 0.f;

    const unsigned short* hb = hbf + l * 8;
#pragma unroll 2
    for (int e = beg + g; e < end; e += 4) {
        int s = eidx[e];
        uint4 pk = *(const uint4*)(hb + (size_t)s * 128);
        union { unsigned u; float f; } t;
        t.u = pk.x << 16;        acc[0] += t.f;
        t.u = pk.x & 0xffff0000u; acc[1] += t.f;
        t.u = pk.y << 16;        acc[2] += t.f;
        t.u = pk.y & 0xffff0000u; acc[3] += t.f;
        t.u = pk.z << 16;        acc[4] += t.f;
        t.u = pk.z & 0xffff0000u; acc[5] += t.f;
        t.u = pk.w << 16;        acc[6] += t.f;
        t.u = pk.w & 0xffff0000u; acc[7] += t.f;
    }
    // reduce across the 4 edge-groups (same l, different g)
#pragma unroll
    for (int j = 0; j < 8; ++j) {
        acc[j] += __shfl_xor(acc[j], 16);
        acc[j] += __shfl_xor(acc[j], 32);
    }
    // this lane finalizes features l*8 + g*2 + {0,1}
    float ax = (g == 0) ? acc[0] : (g == 1) ? acc[2] : (g == 2) ? acc[4] : acc[6];
    float ay = (g == 0) ? acc[1] : (g == 1) ? acc[3] : (g == 2) ? acc[5] : acc[7];

    const int feat = l * 8 + g * 2;
    const float rd = rdeg[node];
    const float2 base = *(const float2*)(outb + (size_t)node * 128 + feat);
    float ox = base.x + ax * rd;
    float oy = base.y + ay * rd;
    *(float2*)(outb + (size_t)node * 128 + feat) = make_float2(ox, oy);

    const float2 wv2 = *(const float2*)(wfc + feat);
    float p = ox * wv2.x + oy * wv2.y;
#pragma unroll
    for (int off = 32; off > 0; off >>= 1) p += __shfl_down(p, off);
    if (lane == 0) ys[node] = p + bfc[0];
}

extern "C" void kernel_launch(void* const* d_in, const int* in_sizes, int n_in,
                              void* d_out, int out_size, void* d_ws, size_t ws_size,
                              hipStream_t stream)
{
    const float* x   = (const float*)d_in[0];
    const int*   ei  = (const int*)d_in[1];
    const float* Wl  = (const float*)d_in[2];
    const float* bl  = (const float*)d_in[3];
    const float* Wr  = (const float*)d_in[4];
    const float* Wfc = (const float*)d_in[5];
    const float* bfc = (const float*)d_in[6];

    const int N = in_sizes[0] / (S_STEPS * D);
    const int E = in_sizes[1] / 2;
    const int* srcp = ei;
    const int* dstp = ei + E;

    char* p = (char*)d_ws;
    auto alloc = [&](size_t bytes) {
        char* r = p;
        p += (bytes + 255) & ~(size_t)255;
        return r;
    };
    int*   cnt     = (int*)alloc((size_t)N * 4);
    int*   row_ptr = (int*)alloc((size_t)(N + 1) * 4);
    int*   fill    = (int*)alloc((size_t)N * 4);
    float* rdeg    = (float*)alloc((size_t)N * 4);
    int*   eidx    = (int*)alloc((size_t)E * 4);
    unsigned short* hbf = (unsigned short*)alloc((size_t)N * D * 2);
    unsigned short* wbf = (unsigned short*)alloc((size_t)256 * 128 * 2);
    (void)ws_size;

    float* xs    = (float*)d_out;
    float* ysall = xs + (size_t)S_STEPS * N * D;

    hipMemsetAsync(cnt, 0, (size_t)N * 4, stream);
    cvtw_kernel<<<128, 256, 0, stream>>>(Wl, Wr, wbf);
    count_kernel<<<(E + 255) / 256, 256, 0, stream>>>(dstp, cnt, E);
    scan_kernel<<<1, 1024, 0, stream>>>(cnt, row_ptr, fill, rdeg, N, E);
    fill_kernel<<<(E + 255) / 256, 256, 0, stream>>>(srcp, dstp, fill, eidx, E);

    const int gl = (N + 63) / 64;
    const int ga = (N + 3) / 4;
    for (int t = 0; t < S_STEPS; ++t) {
        const float* xt = x + (size_t)t * N * D;
        float* outb = xs + (size_t)t * N * D;
        lin_kernel<<<gl, 256, 0, stream>>>(xt, wbf, bl, hbf, outb, N);
        agg_kernel<<<ga, 256, 0, stream>>>(hbf, row_ptr, eidx, rdeg, Wfc, bfc,
                                           outb, ysall + (size_t)t * N, N);
    }
}